// Round 1
// baseline (26.058 us; speedup 1.0000x reference)
//
#include <hip/hip_runtime.h>

// One thread per batch element (3x3 complex matrices).
// Block = 256 threads = 256 batches.
// LDS-staged loads/stores for full coalescing (per-batch stride is 36 B,
// which is neither 16B-aligned nor coalesced; block granularity 9216 B is).

#define BPB 256  // batches per block

__global__ __launch_bounds__(256, 4)
void sun_diffuse_kernel(const float* __restrict__ U0_re, const float* __restrict__ U0_im,
                        const float* __restrict__ xs,
                        const float* __restrict__ V_re, const float* __restrict__ V_im,
                        float* __restrict__ out, int nb)
{
    // layout: Vre[2304] Vim[2304] U0re[2304] U0im[2304] xs[768]  (39936 B)
    __shared__ float smem[2304 * 4 + 768];
    float* sVre  = smem;
    float* sVim  = smem + 2304;
    float* sU0re = smem + 4608;
    float* sU0im = smem + 6912;
    float* sxs   = smem + 9216;

    const int tid = threadIdx.x;
    const int b0  = blockIdx.x * BPB;
    const int nblk = min(BPB, nb - b0);
    const bool full = (nblk == BPB);

    if (full) {
        // 256*9 = 2304 floats = 576 float4 per array; base byte offset b0*36 = blockIdx*9216 (16B aligned)
        const float4* g0 = reinterpret_cast<const float4*>(V_re  + (size_t)b0 * 9);
        const float4* g1 = reinterpret_cast<const float4*>(V_im  + (size_t)b0 * 9);
        const float4* g2 = reinterpret_cast<const float4*>(U0_re + (size_t)b0 * 9);
        const float4* g3 = reinterpret_cast<const float4*>(U0_im + (size_t)b0 * 9);
        float4* s0 = reinterpret_cast<float4*>(sVre);
        float4* s1 = reinterpret_cast<float4*>(sVim);
        float4* s2 = reinterpret_cast<float4*>(sU0re);
        float4* s3 = reinterpret_cast<float4*>(sU0im);
#pragma unroll
        for (int r = 0; r < 3; ++r) {
            int i = tid + r * 256;            // 576 = 2*256 + 64
            if (i < 576) { s0[i] = g0[i]; s1[i] = g1[i]; s2[i] = g2[i]; s3[i] = g3[i]; }
        }
        // xs: 256*3 = 768 floats = 192 float4; byte offset b0*12 = blockIdx*3072 (aligned)
        if (tid < 192)
            reinterpret_cast<float4*>(sxs)[tid] =
                reinterpret_cast<const float4*>(xs + (size_t)b0 * 3)[tid];
    } else {
        const int nf = nblk * 9;
        for (int i = tid; i < nf; i += 256) {
            sVre[i]  = V_re [(size_t)b0 * 9 + i];
            sVim[i]  = V_im [(size_t)b0 * 9 + i];
            sU0re[i] = U0_re[(size_t)b0 * 9 + i];
            sU0im[i] = U0_im[(size_t)b0 * 9 + i];
        }
        for (int i = tid; i < nblk * 3; i += 256) sxs[i] = xs[(size_t)b0 * 3 + i];
    }
    __syncthreads();

    float outr[9], outi[9];
    if (tid < nblk) {
        float vr[9], vi[9], ur[9], ui[9];
#pragma unroll
        for (int m = 0; m < 9; ++m) {
            vr[m] = sVre [tid * 9 + m];
            vi[m] = sVim [tid * 9 + m];
            ur[m] = sU0re[tid * 9 + m];
            ui[m] = sU0im[tid * 9 + m];
        }
        float pr[3], pi[3];
#pragma unroll
        for (int k = 0; k < 3; ++k) {
            float s, c;
            __sincosf(sxs[tid * 3 + k], &s, &c);   // exp(i x) = cos x + i sin x
            pr[k] = c; pi[k] = s;
        }
        // E_ij = sum_k p_k * V_ik * conj(V_jk)
        float Er[9], Ei[9];
#pragma unroll
        for (int i = 0; i < 3; ++i) {
#pragma unroll
            for (int j = 0; j < 3; ++j) {
                float er = 0.f, ei = 0.f;
#pragma unroll
                for (int k = 0; k < 3; ++k) {
                    float wr = pr[k] * vr[i * 3 + k] - pi[k] * vi[i * 3 + k];
                    float wi = pr[k] * vi[i * 3 + k] + pi[k] * vr[i * 3 + k];
                    er += wr * vr[j * 3 + k] + wi * vi[j * 3 + k];
                    ei += wi * vr[j * 3 + k] - wr * vi[j * 3 + k];
                }
                Er[i * 3 + j] = er; Ei[i * 3 + j] = ei;
            }
        }
        // Ut = E @ U0
#pragma unroll
        for (int i = 0; i < 3; ++i) {
#pragma unroll
            for (int j = 0; j < 3; ++j) {
                float r = 0.f, im = 0.f;
#pragma unroll
                for (int k = 0; k < 3; ++k) {
                    r  += Er[i * 3 + k] * ur[k * 3 + j] - Ei[i * 3 + k] * ui[k * 3 + j];
                    im += Er[i * 3 + k] * ui[k * 3 + j] + Ei[i * 3 + k] * ur[k * 3 + j];
                }
                outr[i * 3 + j] = r; outi[i * 3 + j] = im;
            }
        }
    }
    __syncthreads();   // everyone done reading smem before reuse

    // stage output (18 f32/batch, re/im interleaved) into reused smem, then coalesced flush
    float* sOut = smem;  // needs nblk*18 <= 4608 floats: fits in Vre+Vim region
    if (tid < nblk) {
#pragma unroll
        for (int m = 0; m < 9; ++m) {
            sOut[tid * 18 + 2 * m]     = outr[m];
            sOut[tid * 18 + 2 * m + 1] = outi[m];
        }
    }
    __syncthreads();

    if (full) {
        // 256*18 = 4608 floats = 1152 float4; byte offset b0*72 = blockIdx*18432 (aligned)
        float4* gO = reinterpret_cast<float4*>(out + (size_t)b0 * 18);
        const float4* s = reinterpret_cast<const float4*>(sOut);
#pragma unroll
        for (int r = 0; r < 5; ++r) {
            int i = tid + r * 256;            // 1152 = 4*256 + 128
            if (i < 1152) gO[i] = s[i];
        }
    } else {
        const int nf = nblk * 18;
        for (int i = tid; i < nf; i += 256) out[(size_t)b0 * 18 + i] = sOut[i];
    }
}

extern "C" void kernel_launch(void* const* d_in, const int* in_sizes, int n_in,
                              void* d_out, int out_size, void* d_ws, size_t ws_size,
                              hipStream_t stream) {
    const float* U0_re = (const float*)d_in[0];
    const float* U0_im = (const float*)d_in[1];
    const float* xs    = (const float*)d_in[2];
    const float* V_re  = (const float*)d_in[3];
    const float* V_im  = (const float*)d_in[4];
    float* out = (float*)d_out;

    const int nb = in_sizes[2] / 3;            // number of batch elements
    const int grid = (nb + BPB - 1) / BPB;
    sun_diffuse_kernel<<<grid, 256, 0, stream>>>(U0_re, U0_im, xs, V_re, V_im, out, nb);
}

// Round 2
// 25.794 us; speedup vs baseline: 1.0102x; 1.0102x over previous
//
#include <hip/hip_runtime.h>

// One thread per batch element (3x3 complex matrices), 256 batches / block.
// All LDS staging is WAVE-PRIVATE (each wave owns its 64 batches and its own
// smem slice) so there are NO __syncthreads() at all: waves free-run, and
// within-wave ordering is guaranteed by compiler-inserted waitcnts (LDS is
// in-order per wave). Loads/stores are fully coalesced float4 at block/wave
// granularity (per-wave spans: 2304 B per matrix array, 768 B xs, 4608 B out;
// all 16B-aligned).

#define BPB 256  // batches per block (4 waves x 64)

__global__ __launch_bounds__(256, 4)
void sun_diffuse_kernel(const float* __restrict__ U0_re, const float* __restrict__ U0_im,
                        const float* __restrict__ xs,
                        const float* __restrict__ V_re, const float* __restrict__ V_im,
                        float* __restrict__ out, int nb)
{
    // per-wave slice: Vre[576] Vim[576] U0re[576] U0im[576] xs[192] = 2496 f32 (9984 B)
    __shared__ float smem[4][2496];

    const int tid  = threadIdx.x;
    const int w    = tid >> 6;
    const int lane = tid & 63;
    const int b0   = blockIdx.x * BPB;
    const int nblk = min(BPB, nb - b0);
    const bool full = (nblk == BPB);

    float* S     = smem[w];
    float* sVre  = S;
    float* sVim  = S + 576;
    float* sU0re = S + 1152;
    float* sU0im = S + 1728;
    float* sxs   = S + 2304;

    const int wb0 = b0 + w * 64;                       // first batch of this wave
    const int nw  = min(max(nblk - w * 64, 0), 64);    // batches this wave owns

    if (full) {
        // per array: 64*9 = 576 f32 = 144 float4; byte base wb0*36 = 16B-aligned
        const float4* g0 = reinterpret_cast<const float4*>(V_re  + (size_t)wb0 * 9);
        const float4* g1 = reinterpret_cast<const float4*>(V_im  + (size_t)wb0 * 9);
        const float4* g2 = reinterpret_cast<const float4*>(U0_re + (size_t)wb0 * 9);
        const float4* g3 = reinterpret_cast<const float4*>(U0_im + (size_t)wb0 * 9);
        float4* s0 = reinterpret_cast<float4*>(sVre);
        float4* s1 = reinterpret_cast<float4*>(sVim);
        float4* s2 = reinterpret_cast<float4*>(sU0re);
        float4* s3 = reinterpret_cast<float4*>(sU0im);
#pragma unroll
        for (int r = 0; r < 3; ++r) {
            int i = lane + r * 64;                     // 144 = 2*64 + 16
            if (i < 144) { s0[i] = g0[i]; s1[i] = g1[i]; s2[i] = g2[i]; s3[i] = g3[i]; }
        }
        // xs: 64*3 = 192 f32 = 48 float4; byte base wb0*12 = 16B-aligned
        if (lane < 48)
            reinterpret_cast<float4*>(sxs)[lane] =
                reinterpret_cast<const float4*>(xs + (size_t)wb0 * 3)[lane];
    } else {
        for (int i = lane; i < nw * 9; i += 64) {
            sVre[i]  = V_re [(size_t)wb0 * 9 + i];
            sVim[i]  = V_im [(size_t)wb0 * 9 + i];
            sU0re[i] = U0_re[(size_t)wb0 * 9 + i];
            sU0im[i] = U0_im[(size_t)wb0 * 9 + i];
        }
        for (int i = lane; i < nw * 3; i += 64) sxs[i] = xs[(size_t)wb0 * 3 + i];
    }
    // no barrier: wave-private data, compiler waitcnts order vmem->lds->valu

    float outr[9], outi[9];
    if (lane < nw) {
        float vr[9], vi[9], ur[9], ui[9];
#pragma unroll
        for (int m = 0; m < 9; ++m) {
            vr[m] = sVre [lane * 9 + m];
            vi[m] = sVim [lane * 9 + m];
            ur[m] = sU0re[lane * 9 + m];
            ui[m] = sU0im[lane * 9 + m];
        }
        float pr[3], pi[3];
#pragma unroll
        for (int k = 0; k < 3; ++k) {
            float s, c;
            __sincosf(sxs[lane * 3 + k], &s, &c);      // exp(i x) = cos x + i sin x
            pr[k] = c; pi[k] = s;
        }
        // E_ij = sum_k p_k * V_ik * conj(V_jk)
        float Er[9], Ei[9];
#pragma unroll
        for (int i = 0; i < 3; ++i) {
#pragma unroll
            for (int j = 0; j < 3; ++j) {
                float er = 0.f, ei = 0.f;
#pragma unroll
                for (int k = 0; k < 3; ++k) {
                    float wr = pr[k] * vr[i * 3 + k] - pi[k] * vi[i * 3 + k];
                    float wi = pr[k] * vi[i * 3 + k] + pi[k] * vr[i * 3 + k];
                    er += wr * vr[j * 3 + k] + wi * vi[j * 3 + k];
                    ei += wi * vr[j * 3 + k] - wr * vi[j * 3 + k];
                }
                Er[i * 3 + j] = er; Ei[i * 3 + j] = ei;
            }
        }
        // Ut = E @ U0
#pragma unroll
        for (int i = 0; i < 3; ++i) {
#pragma unroll
            for (int j = 0; j < 3; ++j) {
                float r = 0.f, im = 0.f;
#pragma unroll
                for (int k = 0; k < 3; ++k) {
                    r  += Er[i * 3 + k] * ur[k * 3 + j] - Ei[i * 3 + k] * ui[k * 3 + j];
                    im += Er[i * 3 + k] * ui[k * 3 + j] + Ei[i * 3 + k] * ur[k * 3 + j];
                }
                outr[i * 3 + j] = r; outi[i * 3 + j] = im;
            }
        }
    }

    // stage output (18 f32/batch, re/im interleaved) into the wave's own slice
    // (reuses Vre+Vim region: 64*18 = 1152 f32). In-wave LDS ordering keeps the
    // reads above safe; no cross-wave aliasing.
    float* sOut = S;
    if (lane < nw) {
#pragma unroll
        for (int m = 0; m < 9; ++m) {
            sOut[lane * 18 + 2 * m]     = outr[m];
            sOut[lane * 18 + 2 * m + 1] = outi[m];
        }
    }

    if (full) {
        // 64*18 = 1152 f32 = 288 float4; byte base wb0*72 = 16B-aligned
        float4* gO = reinterpret_cast<float4*>(out + (size_t)wb0 * 18);
        const float4* s = reinterpret_cast<const float4*>(sOut);
#pragma unroll
        for (int r = 0; r < 5; ++r) {
            int i = lane + r * 64;                     // 288 = 4*64 + 32
            if (i < 288) gO[i] = s[i];
        }
    } else {
        for (int i = lane; i < nw * 18; i += 64) out[(size_t)wb0 * 18 + i] = sOut[i];
    }
}

extern "C" void kernel_launch(void* const* d_in, const int* in_sizes, int n_in,
                              void* d_out, int out_size, void* d_ws, size_t ws_size,
                              hipStream_t stream) {
    const float* U0_re = (const float*)d_in[0];
    const float* U0_im = (const float*)d_in[1];
    const float* xs    = (const float*)d_in[2];
    const float* V_re  = (const float*)d_in[3];
    const float* V_im  = (const float*)d_in[4];
    float* out = (float*)d_out;

    const int nb = in_sizes[2] / 3;            // number of batch elements
    const int grid = (nb + BPB - 1) / BPB;
    sun_diffuse_kernel<<<grid, 256, 0, stream>>>(U0_re, U0_im, xs, V_re, V_im, out, nb);
}